// Round 2
// baseline (5011.780 us; speedup 1.0000x reference)
//
#include <hip/hip_runtime.h>
#include <math.h>

#define B_    4
#define T_    4096
#define D_    2048
#define H_    16
#define KV_   4
#define DH_   128
#define WIN_  256
#define M_    128
#define ROWS_ (B_ * T_)      // 16384
#define HD_   (H_ * DH_)     // 2048
#define KVD_  (KV_ * DH_)    // 512

// ---------------------------------------------------------------------------
// RoPE cos/sin tables: [T][64]
// ---------------------------------------------------------------------------
__global__ void rope_table_k(float* __restrict__ ct, float* __restrict__ st) {
    int idx = blockIdx.x * 256 + threadIdx.x;
    if (idx >= T_ * 64) return;
    int t = idx >> 6, i = idx & 63;
    float inv = powf(10000.0f, -(2.0f * (float)i) / 128.0f);
    float f = (float)t * inv;
    ct[idx] = cosf(f);
    st[idx] = sinf(f);
}

// ---------------------------------------------------------------------------
// fp32 GEMM: C[m][n] = sum_k A[m][k] * W[n][k]   (A: M x K, W: N x K, row-major)
// 128x128 tile, BK=16, 256 threads, 8x8 acc per thread.
// ---------------------------------------------------------------------------
__global__ __launch_bounds__(256) void gemm_nt_k(
    const float* __restrict__ A, const float* __restrict__ W,
    float* __restrict__ C, int N, int K)
{
    __shared__ float As[16][132];   // [k][m], +4 pad keeps float4 alignment
    __shared__ float Bs[16][132];   // [k][n]
    const int tid = threadIdx.x;
    const int tx = tid & 15, ty = tid >> 4;
    const int m_base = blockIdx.x * 128;
    const int n_base = blockIdx.y * 128;
    const int srow = tid >> 2;   // 0..63
    const int sc4  = tid & 3;    // 0..3  (which float4 of the 16-wide k slab)

    float acc[8][8];
#pragma unroll
    for (int i = 0; i < 8; ++i)
#pragma unroll
        for (int j = 0; j < 8; ++j) acc[i][j] = 0.f;

    for (int k0 = 0; k0 < K; k0 += 16) {
        __syncthreads();
#pragma unroll
        for (int it = 0; it < 2; ++it) {
            int row = srow + it * 64;
            float4 va = *reinterpret_cast<const float4*>(
                &A[(size_t)(m_base + row) * K + k0 + sc4 * 4]);
            As[sc4*4+0][row] = va.x; As[sc4*4+1][row] = va.y;
            As[sc4*4+2][row] = va.z; As[sc4*4+3][row] = va.w;
            float4 vb = *reinterpret_cast<const float4*>(
                &W[(size_t)(n_base + row) * K + k0 + sc4 * 4]);
            Bs[sc4*4+0][row] = vb.x; Bs[sc4*4+1][row] = vb.y;
            Bs[sc4*4+2][row] = vb.z; Bs[sc4*4+3][row] = vb.w;
        }
        __syncthreads();
#pragma unroll
        for (int kk = 0; kk < 16; ++kk) {
            float4 a0 = *reinterpret_cast<const float4*>(&As[kk][ty*8]);
            float4 a1 = *reinterpret_cast<const float4*>(&As[kk][ty*8+4]);
            float4 b0 = *reinterpret_cast<const float4*>(&Bs[kk][tx*8]);
            float4 b1 = *reinterpret_cast<const float4*>(&Bs[kk][tx*8+4]);
            float av[8] = {a0.x,a0.y,a0.z,a0.w,a1.x,a1.y,a1.z,a1.w};
            float bv[8] = {b0.x,b0.y,b0.z,b0.w,b1.x,b1.y,b1.z,b1.w};
#pragma unroll
            for (int i = 0; i < 8; ++i)
#pragma unroll
                for (int j = 0; j < 8; ++j)
                    acc[i][j] = fmaf(av[i], bv[j], acc[i][j]);
        }
    }
#pragma unroll
    for (int i = 0; i < 8; ++i) {
        size_t off = (size_t)(m_base + ty*8 + i) * N + n_base + tx*8;
        float4 o0 = {acc[i][0], acc[i][1], acc[i][2], acc[i][3]};
        float4 o1 = {acc[i][4], acc[i][5], acc[i][6], acc[i][7]};
        *reinterpret_cast<float4*>(&C[off])     = o0;
        *reinterpret_cast<float4*>(&C[off + 4]) = o1;
    }
}

// ---------------------------------------------------------------------------
// In-place interleaved RoPE on a [ROWS][nh*128] buffer; position = row % T.
// ---------------------------------------------------------------------------
__global__ void rope_apply_k(float* buf, const float* __restrict__ ct,
                             const float* __restrict__ st, int nh)
{
    int idx = blockIdx.x * 256 + threadIdx.x;
    int total = ROWS_ * nh * 64;
    if (idx >= total) return;
    int i = idx & 63;
    int h = (idx >> 6) % nh;
    int row = idx / (64 * nh);
    int t = row & (T_ - 1);
    size_t off = ((size_t)row * nh + h) * 128 + 2 * i;
    float2 v = *reinterpret_cast<float2*>(&buf[off]);
    float c = ct[t * 64 + i], s = st[t * 64 + i];
    float2 o;
    o.x = v.x * c - v.y * s;
    o.y = v.x * s + v.y * c;
    *reinterpret_cast<float2*>(&buf[off]) = o;
}

// ---------------------------------------------------------------------------
// Attention over the 384-slot k_full. Block = 256 thr = one (b,h) x 64 q rows.
// Key slot j maps to token row j (j<128) else j+3712. Mask (reference slot
// semantics): j<128 | (qi>=j & qi-j<256). Online softmax; 16-lane groups own
// 4 q-rows each (replicated state); output written in-place over q.
// ---------------------------------------------------------------------------
__global__ __launch_bounds__(256) void attn_k(
    const float* q, const float* __restrict__ kbuf,
    const float* __restrict__ vbuf, float* outb)
{
    __shared__ float Qs[64][132];
    __shared__ float Ks[64][132];
    __shared__ float Vs[64][132];
    const int tid = threadIdx.x;
    const int qt = blockIdx.x;
    const int bh = blockIdx.y;
    const int b  = bh >> 4;
    const int h  = bh & 15;
    const int kv = h >> 2;            // GQA: head h -> kv head h/4
    const int q0 = qt * 64;

    // stage Q tile
#pragma unroll
    for (int it = 0; it < 8; ++it) {
        int fid = tid + it * 256;      // 2048 float4s
        int row = fid >> 5;
        int c4  = fid & 31;
        float4 x = *reinterpret_cast<const float4*>(
            &q[((size_t)(b * T_ + q0 + row) * H_ + h) * 128 + c4 * 4]);
        *reinterpret_cast<float4*>(&Qs[row][c4 * 4]) = x;
    }

    const int g  = tid >> 4;     // row group 0..15 -> rows 4g..4g+3
    const int c  = tid & 15;     // key lane: keys {c, c+16, c+32, c+48} in tile
    const int r0 = g * 4;
    const int d0 = c * 8;        // dims owned in PV phase

    float mrow[4], lrow[4], accd[4][8];
#pragma unroll
    for (int i = 0; i < 4; ++i) {
        mrow[i] = -INFINITY; lrow[i] = 0.f;
#pragma unroll
        for (int d = 0; d < 8; ++d) accd[i][d] = 0.f;
    }
    const float scale = 0.08838834764831845f;  // 1/sqrt(128)

    for (int kt = 0; kt < 6; ++kt) {
        int j0 = kt * 64;
        // tile needed iff sink tile, or slot range intersects [q0-255, q0+63]
        bool needed = (kt < 2) || ((j0 <= q0 + 63) && (j0 + 63 >= q0 - 255));
        if (!needed) continue;      // block-uniform -> barrier-safe
        __syncthreads();
#pragma unroll
        for (int it = 0; it < 8; ++it) {
            int fid = tid + it * 256;
            int row = fid >> 5;
            int c4  = fid & 31;
            int j   = j0 + row;
            int trow = (j < M_) ? j : j + (T_ - WIN_ - M_);   // +3712
            size_t base = ((size_t)(b * T_ + trow) * KV_ + kv) * 128 + c4 * 4;
            *reinterpret_cast<float4*>(&Ks[row][c4 * 4]) =
                *reinterpret_cast<const float4*>(&kbuf[base]);
            *reinterpret_cast<float4*>(&Vs[row][c4 * 4]) =
                *reinterpret_cast<const float4*>(&vbuf[base]);
        }
        __syncthreads();

        // QK^T
        float s[4][4];
#pragma unroll
        for (int i = 0; i < 4; ++i)
#pragma unroll
            for (int jj = 0; jj < 4; ++jj) s[i][jj] = 0.f;
#pragma unroll 2
        for (int d = 0; d < 128; d += 4) {
            float4 qa[4], kb[4];
#pragma unroll
            for (int i = 0; i < 4; ++i)
                qa[i] = *reinterpret_cast<const float4*>(&Qs[r0 + i][d]);
#pragma unroll
            for (int jj = 0; jj < 4; ++jj)
                kb[jj] = *reinterpret_cast<const float4*>(&Ks[c + 16 * jj][d]);
#pragma unroll
            for (int i = 0; i < 4; ++i)
#pragma unroll
                for (int jj = 0; jj < 4; ++jj) {
                    s[i][jj] = fmaf(qa[i].x, kb[jj].x, s[i][jj]);
                    s[i][jj] = fmaf(qa[i].y, kb[jj].y, s[i][jj]);
                    s[i][jj] = fmaf(qa[i].z, kb[jj].z, s[i][jj]);
                    s[i][jj] = fmaf(qa[i].w, kb[jj].w, s[i][jj]);
                }
        }

        // scale + mask + tile row-max
        float tmax[4];
#pragma unroll
        for (int i = 0; i < 4; ++i) {
            int qi = q0 + r0 + i;
            tmax[i] = -INFINITY;
#pragma unroll
            for (int jj = 0; jj < 4; ++jj) {
                int kj = j0 + c + 16 * jj;
                float sv = s[i][jj] * scale;
                bool valid = (kj < M_) || ((qi >= kj) && (qi - kj < WIN_));
                sv = valid ? sv : -INFINITY;
                s[i][jj] = sv;
                tmax[i] = fmaxf(tmax[i], sv);
            }
        }
#pragma unroll
        for (int off = 1; off < 16; off <<= 1)
#pragma unroll
            for (int i = 0; i < 4; ++i)
                tmax[i] = fmaxf(tmax[i], __shfl_xor(tmax[i], off, 16));

        // online softmax update
        float p[4][4], rsum[4];
#pragma unroll
        for (int i = 0; i < 4; ++i) {
            float mnew = fmaxf(mrow[i], tmax[i]);
            float sc = expf(mrow[i] - mnew);   // tile 0 all-valid -> no inf-inf
            mrow[i] = mnew;
            rsum[i] = 0.f;
#pragma unroll
            for (int jj = 0; jj < 4; ++jj) {
                p[i][jj] = expf(s[i][jj] - mnew);
                rsum[i] += p[i][jj];
            }
            lrow[i] *= sc;
#pragma unroll
            for (int d = 0; d < 8; ++d) accd[i][d] *= sc;
        }
#pragma unroll
        for (int off = 1; off < 16; off <<= 1)
#pragma unroll
            for (int i = 0; i < 4; ++i)
                rsum[i] += __shfl_xor(rsum[i], off, 16);
#pragma unroll
        for (int i = 0; i < 4; ++i) lrow[i] += rsum[i];

        // PV: broadcast p across the 16-lane group, accumulate 8 dims/lane
#pragma unroll
        for (int jj = 0; jj < 4; ++jj) {
            for (int src = 0; src < 16; ++src) {
                int key = jj * 16 + src;          // tile slot = src + 16*jj
                float pp[4];
#pragma unroll
                for (int i = 0; i < 4; ++i) pp[i] = __shfl(p[i][jj], src, 16);
                float4 va = *reinterpret_cast<const float4*>(&Vs[key][d0]);
                float4 vb = *reinterpret_cast<const float4*>(&Vs[key][d0 + 4]);
#pragma unroll
                for (int i = 0; i < 4; ++i) {
                    accd[i][0] = fmaf(pp[i], va.x, accd[i][0]);
                    accd[i][1] = fmaf(pp[i], va.y, accd[i][1]);
                    accd[i][2] = fmaf(pp[i], va.z, accd[i][2]);
                    accd[i][3] = fmaf(pp[i], va.w, accd[i][3]);
                    accd[i][4] = fmaf(pp[i], vb.x, accd[i][4]);
                    accd[i][5] = fmaf(pp[i], vb.y, accd[i][5]);
                    accd[i][6] = fmaf(pp[i], vb.z, accd[i][6]);
                    accd[i][7] = fmaf(pp[i], vb.w, accd[i][7]);
                }
            }
        }
    }

    // normalize + write (in-place over q; disjoint (row,head,dim) per lane)
#pragma unroll
    for (int i = 0; i < 4; ++i) {
        float inv = 1.0f / lrow[i];
        size_t off = ((size_t)(b * T_ + q0 + r0 + i) * H_ + h) * 128 + d0;
        float4 o0 = {accd[i][0]*inv, accd[i][1]*inv, accd[i][2]*inv, accd[i][3]*inv};
        float4 o1 = {accd[i][4]*inv, accd[i][5]*inv, accd[i][6]*inv, accd[i][7]*inv};
        *reinterpret_cast<float4*>(&outb[off])     = o0;
        *reinterpret_cast<float4*>(&outb[off + 4]) = o1;
    }
}

// ---------------------------------------------------------------------------
extern "C" void kernel_launch(void* const* d_in, const int* in_sizes, int n_in,
                              void* d_out, int out_size, void* d_ws, size_t ws_size,
                              hipStream_t stream)
{
    const float* x  = (const float*)d_in[0];
    const float* wq = (const float*)d_in[1];
    const float* wk = (const float*)d_in[2];
    const float* wv = (const float*)d_in[3];
    const float* wo = (const float*)d_in[4];
    float* out = (float*)d_out;
    float* ws  = (float*)d_ws;

    const size_t qn = (size_t)ROWS_ * HD_;    // 33.5M floats
    const size_t kn = (size_t)ROWS_ * KVD_;   // 8.4M floats
    const size_t tn = (size_t)T_ * 64;        // 262K floats
    if (ws_size < (qn + 2 * kn + 2 * tn) * sizeof(float)) return; // ws too small

    float* qb = ws;
    float* kb = qb + qn;
    float* vb = kb + kn;
    float* ct = vb + kn;
    float* st = ct + tn;

    rope_table_k<<<(T_ * 64 + 255) / 256, 256, 0, stream>>>(ct, st);

    dim3 gq(ROWS_ / 128, HD_ / 128);
    gemm_nt_k<<<gq, 256, 0, stream>>>(x, wq, qb, HD_, D_);
    dim3 gkv(ROWS_ / 128, KVD_ / 128);
    gemm_nt_k<<<gkv, 256, 0, stream>>>(x, wk, kb, KVD_, D_);
    gemm_nt_k<<<gkv, 256, 0, stream>>>(x, wv, vb, KVD_, D_);

    rope_apply_k<<<(ROWS_ * H_  * 64) / 256, 256, 0, stream>>>(qb, ct, st, H_);
    rope_apply_k<<<(ROWS_ * KV_ * 64) / 256, 256, 0, stream>>>(kb, ct, st, KV_);

    dim3 ga(T_ / 64, B_ * H_);
    attn_k<<<ga, 256, 0, stream>>>(qb, kb, vb, qb);

    dim3 go(ROWS_ / 128, D_ / 128);
    gemm_nt_k<<<go, 256, 0, stream>>>(qb, wo, out, D_, D_);
}